// Round 1
// baseline (1200.668 us; speedup 1.0000x reference)
//
#include <hip/hip_runtime.h>
#include <hip/hip_bf16.h>
#include <math.h>

// Problem constants
#define B_ 2
#define S_ 2048
#define D_ 1024
#define H_ 16
#define DK_ 64
// qkv width
#define N3D_ 3072

// ---------------------------------------------------------------------------
// Kernel 1: qkv = X[4096,1024] @ Wqkv[1024,3072]; epilogue applies RoPE to the
// Q and K regions and scatters Q,K,V into [B,H,S,DK] workspaces.
// Tile 64x64, BK=16, 256 threads (16x16), 4x4 micro-tile per thread.
// ---------------------------------------------------------------------------
__global__ __launch_bounds__(256) void qkv_rope_gemm(
    const float* __restrict__ X, const float* __restrict__ W,
    const int* __restrict__ pos,
    float* __restrict__ qws, float* __restrict__ kws, float* __restrict__ vws)
{
    __shared__ float As[16][64];   // [k][m]
    __shared__ float Bs[16][64];   // [k][n]
    const int m0 = blockIdx.x * 64;
    const int n0 = blockIdx.y * 64;
    const int t  = threadIdx.x;
    const int tx = t & 15, ty = t >> 4;

    float acc[4][4] = {};

    const int arow = t >> 2, ac4 = (t & 3) << 2;   // A: 64 rows x 16 cols
    const int brow = t >> 4, bc4 = (t & 15) << 2;  // B: 16 rows x 64 cols

    for (int k0 = 0; k0 < D_; k0 += 16) {
        float4 av = *(const float4*)&X[(size_t)(m0 + arow) * D_ + k0 + ac4];
        float4 bv = *(const float4*)&W[(size_t)(k0 + brow) * N3D_ + n0 + bc4];
        As[ac4 + 0][arow] = av.x;
        As[ac4 + 1][arow] = av.y;
        As[ac4 + 2][arow] = av.z;
        As[ac4 + 3][arow] = av.w;
        *(float4*)&Bs[brow][bc4] = bv;
        __syncthreads();
#pragma unroll
        for (int k = 0; k < 16; ++k) {
            float a[4], b[4];
#pragma unroll
            for (int i = 0; i < 4; ++i) a[i] = As[k][ty * 4 + i];
#pragma unroll
            for (int j = 0; j < 4; ++j) b[j] = Bs[k][tx * 4 + j];
#pragma unroll
            for (int i = 0; i < 4; ++i)
#pragma unroll
                for (int j = 0; j < 4; ++j) acc[i][j] += a[i] * b[j];
        }
        __syncthreads();
    }

    // Epilogue: whole block is within one region (Q/K/V) and one head,
    // since n0 is a multiple of 64 and regions are multiples of 1024.
    const int region = n0 >> 10;          // 0=Q, 1=K, 2=V
    const int h      = (n0 & 1023) >> 6;  // head index
    float* dst = (region == 0) ? qws : (region == 1) ? kws : vws;

#pragma unroll
    for (int i = 0; i < 4; ++i) {
        const int m = m0 + ty * 4 + i;
        const int b = m >> 11;          // / S_
        const int s = m & (S_ - 1);
        float* drow = dst + (((size_t)(b * H_ + h) * S_ + s) << 6);
        if (region < 2) {
            const int p = pos[s];
#pragma unroll
            for (int jj = 0; jj < 2; ++jj) {
                const int c = tx * 4 + jj * 2;          // even col within head
                // inv_freq = theta^{-c/dk}
                const float freq = __powf(10000.0f, -(float)c * (1.0f / 64.0f));
                const float ang  = (float)p * freq;
                float sn, cs;
                sincosf(ang, &sn, &cs);
                const float x1 = acc[i][jj * 2];
                const float x2 = acc[i][jj * 2 + 1];
                drow[c]     = x1 * cs - x2 * sn;
                drow[c + 1] = x1 * sn + x2 * cs;
            }
        } else {
#pragma unroll
            for (int j = 0; j < 4; ++j) drow[tx * 4 + j] = acc[i][j];
        }
    }
}

// ---------------------------------------------------------------------------
// Kernel 2: fp32 flash attention, causal. Grid (qt=S/64, bh=B*H).
// 256 threads (16x16), 4x4 micro-tile of the 64x64 score tile per thread.
// Q,K,V in [B*H, S, DK] layout (from kernel 1). Output [B,S,D].
// ---------------------------------------------------------------------------
__global__ __launch_bounds__(256) void flash_attn(
    const float* __restrict__ Q, const float* __restrict__ K,
    const float* __restrict__ V, float* __restrict__ O)
{
    __shared__ float Qs[64][65];
    __shared__ float Ks[64][65];
    __shared__ float Vs[64][65];
    __shared__ float Ps[64][65];

    const int qt = blockIdx.x;   // query tile 0..31
    const int bh = blockIdx.y;   // 0..31
    const int t  = threadIdx.x;
    const int tx = t & 15, ty = t >> 4;

    const float* Qp = Q + ((size_t)bh * S_ + qt * 64) * DK_;
    for (int idx = t; idx < 64 * 16; idx += 256) {
        const int r = idx >> 4, c4 = (idx & 15) << 2;
        float4 v = *(const float4*)&Qp[r * DK_ + c4];
        Qs[r][c4 + 0] = v.x * 0.125f;   // fold in 1/sqrt(64)
        Qs[r][c4 + 1] = v.y * 0.125f;
        Qs[r][c4 + 2] = v.z * 0.125f;
        Qs[r][c4 + 3] = v.w * 0.125f;
    }

    float m_i[4], l_i[4], o[4][4];
#pragma unroll
    for (int i = 0; i < 4; ++i) {
        m_i[i] = -1e30f; l_i[i] = 0.0f;
#pragma unroll
        for (int j = 0; j < 4; ++j) o[i][j] = 0.0f;
    }

    for (int kt = 0; kt <= qt; ++kt) {
        __syncthreads();  // previous PV reads done (first iter: Q stores done)
        const float* Kp = K + ((size_t)bh * S_ + kt * 64) * DK_;
        const float* Vp = V + ((size_t)bh * S_ + kt * 64) * DK_;
        for (int idx = t; idx < 64 * 16; idx += 256) {
            const int r = idx >> 4, c4 = (idx & 15) << 2;
            float4 kv = *(const float4*)&Kp[r * DK_ + c4];
            Ks[r][c4 + 0] = kv.x; Ks[r][c4 + 1] = kv.y;
            Ks[r][c4 + 2] = kv.z; Ks[r][c4 + 3] = kv.w;
            float4 vv = *(const float4*)&Vp[r * DK_ + c4];
            Vs[r][c4 + 0] = vv.x; Vs[r][c4 + 1] = vv.y;
            Vs[r][c4 + 2] = vv.z; Vs[r][c4 + 3] = vv.w;
        }
        __syncthreads();

        float sc[4][4] = {};
#pragma unroll
        for (int d = 0; d < DK_; ++d) {
            float qa[4], kb[4];
#pragma unroll
            for (int i = 0; i < 4; ++i) qa[i] = Qs[ty * 4 + i][d];
#pragma unroll
            for (int j = 0; j < 4; ++j) kb[j] = Ks[tx * 4 + j][d];
#pragma unroll
            for (int i = 0; i < 4; ++i)
#pragma unroll
                for (int j = 0; j < 4; ++j) sc[i][j] += qa[i] * kb[j];
        }

        if (kt == qt) {
#pragma unroll
            for (int i = 0; i < 4; ++i)
#pragma unroll
                for (int j = 0; j < 4; ++j)
                    if (tx * 4 + j > ty * 4 + i) sc[i][j] = -1e30f;
        }

#pragma unroll
        for (int i = 0; i < 4; ++i) {
            float mx = fmaxf(fmaxf(sc[i][0], sc[i][1]), fmaxf(sc[i][2], sc[i][3]));
#pragma unroll
            for (int off = 1; off < 16; off <<= 1) mx = fmaxf(mx, __shfl_xor(mx, off));
            const float mnew = fmaxf(m_i[i], mx);
            const float alpha = __expf(m_i[i] - mnew);
            m_i[i] = mnew;
            float rs = 0.0f;
#pragma unroll
            for (int j = 0; j < 4; ++j) {
                sc[i][j] = __expf(sc[i][j] - mnew);
                rs += sc[i][j];
            }
#pragma unroll
            for (int off = 1; off < 16; off <<= 1) rs += __shfl_xor(rs, off);
            l_i[i] = l_i[i] * alpha + rs;
#pragma unroll
            for (int j = 0; j < 4; ++j) {
                o[i][j] *= alpha;
                Ps[ty * 4 + i][tx * 4 + j] = sc[i][j];
            }
        }
        __syncthreads();

#pragma unroll
        for (int k = 0; k < 64; ++k) {
            float pv[4], vv[4];
#pragma unroll
            for (int i = 0; i < 4; ++i) pv[i] = Ps[ty * 4 + i][k];
#pragma unroll
            for (int j = 0; j < 4; ++j) vv[j] = Vs[k][tx * 4 + j];
#pragma unroll
            for (int i = 0; i < 4; ++i)
#pragma unroll
                for (int j = 0; j < 4; ++j) o[i][j] += pv[i] * vv[j];
        }
    }

    // Epilogue: normalize and scatter to [B,S,D]
    const int b = bh >> 4, h = bh & 15;
#pragma unroll
    for (int i = 0; i < 4; ++i) {
        const int s = qt * 64 + ty * 4 + i;
        const float inv = 1.0f / l_i[i];
        float* orow = O + ((size_t)(b * S_ + s) * D_) + h * DK_;
#pragma unroll
        for (int j = 0; j < 4; ++j) orow[tx * 4 + j] = o[i][j] * inv;
    }
}

// ---------------------------------------------------------------------------
// Kernel 3: out = attn[4096,1024] @ Wo[1024,1024]
// ---------------------------------------------------------------------------
__global__ __launch_bounds__(256) void out_gemm(
    const float* __restrict__ X, const float* __restrict__ W,
    float* __restrict__ C)
{
    __shared__ float As[16][64];
    __shared__ float Bs[16][64];
    const int m0 = blockIdx.x * 64;
    const int n0 = blockIdx.y * 64;
    const int t  = threadIdx.x;
    const int tx = t & 15, ty = t >> 4;

    float acc[4][4] = {};

    const int arow = t >> 2, ac4 = (t & 3) << 2;
    const int brow = t >> 4, bc4 = (t & 15) << 2;

    for (int k0 = 0; k0 < D_; k0 += 16) {
        float4 av = *(const float4*)&X[(size_t)(m0 + arow) * D_ + k0 + ac4];
        float4 bv = *(const float4*)&W[(size_t)(k0 + brow) * D_ + n0 + bc4];
        As[ac4 + 0][arow] = av.x;
        As[ac4 + 1][arow] = av.y;
        As[ac4 + 2][arow] = av.z;
        As[ac4 + 3][arow] = av.w;
        *(float4*)&Bs[brow][bc4] = bv;
        __syncthreads();
#pragma unroll
        for (int k = 0; k < 16; ++k) {
            float a[4], b[4];
#pragma unroll
            for (int i = 0; i < 4; ++i) a[i] = As[k][ty * 4 + i];
#pragma unroll
            for (int j = 0; j < 4; ++j) b[j] = Bs[k][tx * 4 + j];
#pragma unroll
            for (int i = 0; i < 4; ++i)
#pragma unroll
                for (int j = 0; j < 4; ++j) acc[i][j] += a[i] * b[j];
        }
        __syncthreads();
    }

#pragma unroll
    for (int i = 0; i < 4; ++i) {
        const int m = m0 + ty * 4 + i;
        float4 v = make_float4(acc[i][0], acc[i][1], acc[i][2], acc[i][3]);
        *(float4*)&C[(size_t)m * D_ + n0 + tx * 4] = v;
    }
}

// ---------------------------------------------------------------------------
extern "C" void kernel_launch(void* const* d_in, const int* in_sizes, int n_in,
                              void* d_out, int out_size, void* d_ws, size_t ws_size,
                              hipStream_t stream) {
    const float* X    = (const float*)d_in[0];  // [B,S,D]
    const int*   pos  = (const int*)d_in[1];    // [S]
    const float* Wqkv = (const float*)d_in[2];  // [D,3D]
    const float* Wo   = (const float*)d_in[3];  // [D,D]
    float* out = (float*)d_out;                 // [B,S,D]

    const size_t QSZ = (size_t)B_ * H_ * S_ * DK_;  // 4M floats
    float* qws = (float*)d_ws;
    float* kws = qws + QSZ;
    float* vws = kws + QSZ;
    float* aws = vws + QSZ;  // [B,S,D] attn output

    qkv_rope_gemm<<<dim3(64, 48), 256, 0, stream>>>(X, Wqkv, pos, qws, kws, vws);
    flash_attn<<<dim3(32, 32), 256, 0, stream>>>(qws, kws, vws, aws);
    out_gemm<<<dim3(64, 16), 256, 0, stream>>>(aws, Wo, out);
}

// Round 2
// 197.303 us; speedup vs baseline: 6.0854x; 6.0854x over previous
//
#include <hip/hip_runtime.h>
#include <hip/hip_bf16.h>
#include <math.h>

typedef unsigned short u16;
typedef unsigned int u32;
typedef __attribute__((ext_vector_type(4))) float f32x4;
typedef __attribute__((ext_vector_type(8))) short bf16x8;

#define B_ 2
#define S_ 2048
#define D_ 1024
#define H_ 16
#define DK_ 64

__device__ __forceinline__ u16 f2bf(float x) {
    union { __hip_bfloat16 h; u16 u; } v;
    v.h = __float2bfloat16(x);
    return v.u;
}

__device__ __forceinline__ void gload_lds16(const u16* g, u16* l) {
    __builtin_amdgcn_global_load_lds(
        (const __attribute__((address_space(1))) unsigned int*)g,
        (__attribute__((address_space(3))) unsigned int*)l, 16, 0, 0);
}

// ---------------------------------------------------------------------------
// Prep: cast fp32 -> bf16 (X)
// ---------------------------------------------------------------------------
__global__ __launch_bounds__(256) void cast_bf16_kernel(
    const float* __restrict__ in, u16* __restrict__ outp, int n)
{
    const int i = (blockIdx.x * 256 + threadIdx.x) * 8;
    if (i >= n) return;
    float4 a = *(const float4*)(in + i);
    float4 b = *(const float4*)(in + i + 4);
    u32 p0 = (u32)f2bf(a.x) | ((u32)f2bf(a.y) << 16);
    u32 p1 = (u32)f2bf(a.z) | ((u32)f2bf(a.w) << 16);
    u32 p2 = (u32)f2bf(b.x) | ((u32)f2bf(b.y) << 16);
    u32 p3 = (u32)f2bf(b.z) | ((u32)f2bf(b.w) << 16);
    *(uint4*)(outp + i) = make_uint4(p0, p1, p2, p3);
}

// ---------------------------------------------------------------------------
// Prep: W [1024][N] fp32 -> WT [N][1024] bf16  (64x64 tiles via LDS)
// ---------------------------------------------------------------------------
__global__ __launch_bounds__(256) void transpose_cast(
    const float* __restrict__ W, u16* __restrict__ WT, int N)
{
    __shared__ float tile[64][65];
    const int k0 = blockIdx.x * 64, n0 = blockIdx.y * 64;
    const int t = threadIdx.x;
    const int r = t >> 4, c4 = (t & 15) * 4;
#pragma unroll
    for (int p = 0; p < 4; ++p) {
        float4 v = *(const float4*)&W[(size_t)(k0 + r + p * 16) * N + n0 + c4];
        tile[r + p * 16][c4 + 0] = v.x;
        tile[r + p * 16][c4 + 1] = v.y;
        tile[r + p * 16][c4 + 2] = v.z;
        tile[r + p * 16][c4 + 3] = v.w;
    }
    __syncthreads();
    const int nl = t >> 2, kc = (t & 3) * 16;
    u16 buf[16];
#pragma unroll
    for (int j = 0; j < 16; ++j) buf[j] = f2bf(tile[kc + j][nl]);
    const size_t idx = (size_t)(n0 + nl) * 1024 + k0 + kc;
    u32 px[8];
#pragma unroll
    for (int j = 0; j < 8; ++j) px[j] = (u32)buf[2 * j] | ((u32)buf[2 * j + 1] << 16);
    *(uint4*)&WT[idx]     = make_uint4(px[0], px[1], px[2], px[3]);
    *(uint4*)&WT[idx + 8] = make_uint4(px[4], px[5], px[6], px[7]);
}

// ---------------------------------------------------------------------------
// Prep: RoPE table  tab[s*32 + j] = (cos, sin)(pos[s] * 10000^(-2j/64))
// ---------------------------------------------------------------------------
__global__ __launch_bounds__(256) void rope_table_kernel(
    const int* __restrict__ pos, float2* __restrict__ tab)
{
    const int i = blockIdx.x * 256 + threadIdx.x;  // 2048*32
    const int s = i >> 5, j = i & 31;
    const float freq = __powf(10000.f, -(float)(2 * j) * (1.f / 64.f));
    const float ang = (float)pos[s] * freq;
    float sn, cs;
    sincosf(ang, &sn, &cs);
    tab[i] = make_float2(cs, sn);
}

// ---------------------------------------------------------------------------
// Shared GEMM mainloop: C[128x128] = A[m0..][K] * BT[n0..][K]^T, bf16 MFMA.
// 256 thr = 4 waves (2x2), each wave 4x4 frags of 16x16x32. BK=32.
// LDS rows 64B, XOR-swizzle cg^=(row&3) staged via pre-swizzled global src.
// ---------------------------------------------------------------------------
__device__ __forceinline__ void gemm_mainloop_128(
    const u16* __restrict__ A, const u16* __restrict__ BT, int K,
    int m0, int n0, int l, int w, u16* lA, u16* lB, f32x4 acc[4][4])
{
    const int wr = w >> 1, wc = w & 1, lr = l & 15, lg = l >> 4;
    const int rowA = w * 32 + (l >> 2);
    const int cgs = (l & 3) ^ (rowA & 3);   // (row+16)&3 == row&3, so valid for both halves
    const u16* gA = A + (size_t)(m0 + rowA) * K + cgs * 8;
    const u16* gB = BT + (size_t)(n0 + rowA) * K + cgs * 8;

    for (int k0 = 0; k0 < K; k0 += 32) {
        gload_lds16(gA,          lA + w * 1024);
        gload_lds16(gA + 16 * K, lA + w * 1024 + 512);
        gload_lds16(gB,          lB + w * 1024);
        gload_lds16(gB + 16 * K, lB + w * 1024 + 512);
        gA += 32; gB += 32;
        asm volatile("s_waitcnt vmcnt(0)" ::: "memory");
        __syncthreads();
        bf16x8 a[4], b[4];
#pragma unroll
        for (int i = 0; i < 4; ++i) {
            const int row = wr * 64 + i * 16 + lr;
            a[i] = *(const bf16x8*)(lA + row * 32 + (lg ^ (row & 3)) * 8);
        }
#pragma unroll
        for (int j = 0; j < 4; ++j) {
            const int row = wc * 64 + j * 16 + lr;
            b[j] = *(const bf16x8*)(lB + row * 32 + (lg ^ (row & 3)) * 8);
        }
#pragma unroll
        for (int i = 0; i < 4; ++i)
#pragma unroll
            for (int j = 0; j < 4; ++j)
                acc[i][j] = __builtin_amdgcn_mfma_f32_16x16x32_bf16(a[i], b[j], acc[i][j], 0, 0, 0);
        __syncthreads();
    }
}

// ---------------------------------------------------------------------------
// Kernel: QKV GEMM + RoPE epilogue. A=Xb[4096][1024], BT=WqkvT[3072][1024].
// Q (scaled 0.125) and K roped -> [B,H,S,DK] bf16; V -> [B,H,DK,S] bf16 (V^T).
// ---------------------------------------------------------------------------
__global__ __launch_bounds__(256) void gemm_qkv_rope(
    const u16* __restrict__ A, const u16* __restrict__ BT,
    const float2* __restrict__ tab,
    u16* __restrict__ qo, u16* __restrict__ ko, u16* __restrict__ vto)
{
    __shared__ u16 lA[128 * 32];
    __shared__ u16 lB[128 * 32];
    const int t = threadIdx.x, l = t & 63, w = t >> 6;
    const int m0 = blockIdx.x * 128, n0 = blockIdx.y * 128;
    f32x4 acc[4][4] = {};
    gemm_mainloop_128(A, BT, 1024, m0, n0, l, w, lA, lB, acc);

    const int wr = w >> 1, wc = w & 1, lr = l & 15, lg = l >> 4;
    const int region = n0 >> 10;  // 0=Q,1=K,2=V (tile never crosses regions)

    if (region < 2) {
        u16* dst = (region == 0) ? qo : ko;
        const float qscale = (region == 0) ? 0.125f : 1.0f;
#pragma unroll
        for (int j = 0; j < 4; ++j) {
            const int nb = n0 + wc * 64 + j * 16;
            const int h = (nb >> 6) & 15;
            const int c = j * 16 + lr;          // 0..63 within head
#pragma unroll
            for (int i = 0; i < 4; ++i) {
#pragma unroll
                for (int r = 0; r < 4; ++r) {
                    const int m = m0 + wr * 64 + i * 16 + lg * 4 + r;
                    const int bb = m >> 11, s = m & (S_ - 1);
                    const float2 cs = tab[s * 32 + (c >> 1)];
                    const float v = acc[i][j][r];
                    const float vp = __shfl_xor(v, 1);
                    float outv = ((lr & 1) == 0) ? (v * cs.x - vp * cs.y)
                                                 : (v * cs.x + vp * cs.y);
                    outv *= qscale;
                    dst[(((size_t)bb * H_ + h) * S_ + s) * DK_ + c] = f2bf(outv);
                }
            }
        }
    } else {
#pragma unroll
        for (int j = 0; j < 4; ++j) {
            const int nb = n0 + wc * 64 + j * 16;
            const int h = (nb >> 6) & 15;
            const int c = j * 16 + lr;
#pragma unroll
            for (int i = 0; i < 4; ++i) {
#pragma unroll
                for (int r = 0; r < 4; ++r) {
                    const int m = m0 + wr * 64 + i * 16 + lg * 4 + r;
                    const int bb = m >> 11, s = m & (S_ - 1);
                    vto[(((size_t)bb * H_ + h) * DK_ + c) * S_ + s] = f2bf(acc[i][j][r]);
                }
            }
        }
    }
}

// ---------------------------------------------------------------------------
// Kernel: MFMA flash attention. Grid (qt=32, bh=32), 256 thr = 4 waves.
// Wave w owns q rows qt*64 + w*16 .. +15. K tiles of 64 keys.
// Q,K: [B,H,S,64] bf16; VT: [B,H,64,S] bf16. Out: [B,S,D] bf16.
// LDS K/Q/V rows 128B with cg^=(row&7) XOR swizzle (staged pre-swizzled).
// ---------------------------------------------------------------------------
__global__ __launch_bounds__(256) void attn_mfma(
    const u16* __restrict__ Qg, const u16* __restrict__ Kg,
    const u16* __restrict__ VTg, u16* __restrict__ Og)
{
    __shared__ u16 sQ[64 * 64];
    __shared__ u16 sK[64 * 64];
    __shared__ u16 sV[64 * 64];       // V^T tile: [dk][key]
    __shared__ u16 sP[4][16 * 72];    // per-wave P [16 q][64 keys], 144B rows
    const int t = threadIdx.x, l = t & 63, w = t >> 6;
    const int qt = blockIdx.x, bh = blockIdx.y;
    const int lr = l & 15, lg = l >> 4;

    // stage Q tile (once), pre-swizzled source
#pragma unroll
    for (int q = 0; q < 2; ++q) {
        const int row = w * 16 + q * 8 + (l >> 3);
        const int cg = (l & 7) ^ (row & 7);
        gload_lds16(Qg + ((size_t)bh * S_ + qt * 64 + row) * DK_ + cg * 8,
                    sQ + w * 1024 + q * 512);
    }

    f32x4 o[4] = {};
    float mi[4], li[4];
#pragma unroll
    for (int r = 0; r < 4; ++r) { mi[r] = -3.0e38f; li[r] = 0.f; }

    for (int kt = 0; kt <= qt; ++kt) {
        __syncthreads();   // previous tile's compute done before overwrite
#pragma unroll
        for (int q = 0; q < 2; ++q) {
            const int row = w * 16 + q * 8 + (l >> 3);
            const int cg = (l & 7) ^ (row & 7);
            gload_lds16(Kg + ((size_t)bh * S_ + kt * 64 + row) * DK_ + cg * 8,
                        sK + w * 1024 + q * 512);
            gload_lds16(VTg + ((size_t)bh * DK_ + row) * S_ + kt * 64 + cg * 8,
                        sV + w * 1024 + q * 512);
        }
        asm volatile("s_waitcnt vmcnt(0)" ::: "memory");
        __syncthreads();

        // ---- QK^T: wave's 16q x 64key stripe ----
        bf16x8 qa[2];
#pragma unroll
        for (int ks = 0; ks < 2; ++ks) {
            const int row = w * 16 + lr;
            qa[ks] = *(const bf16x8*)(sQ + row * 64 + ((ks * 4 + lg) ^ (row & 7)) * 8);
        }
        f32x4 s4[4] = {};
#pragma unroll
        for (int kf = 0; kf < 4; ++kf) {
#pragma unroll
            for (int ks = 0; ks < 2; ++ks) {
                const int row = kf * 16 + lr;
                bf16x8 kb = *(const bf16x8*)(sK + row * 64 + ((ks * 4 + lg) ^ (row & 7)) * 8);
                s4[kf] = __builtin_amdgcn_mfma_f32_16x16x32_bf16(qa[ks], kb, s4[kf], 0, 0, 0);
            }
        }
        if (kt == qt) {
#pragma unroll
            for (int kf = 0; kf < 4; ++kf)
#pragma unroll
                for (int r = 0; r < 4; ++r)
                    if (kf * 16 + lr > w * 16 + lg * 4 + r) s4[kf][r] = -3.0e38f;
        }

        // ---- online softmax (lane owns rows lg*4+r; cols spread over lr,kf) ----
#pragma unroll
        for (int r = 0; r < 4; ++r) {
            float mx = fmaxf(fmaxf(s4[0][r], s4[1][r]), fmaxf(s4[2][r], s4[3][r]));
            mx = fmaxf(mx, __shfl_xor(mx, 1));
            mx = fmaxf(mx, __shfl_xor(mx, 2));
            mx = fmaxf(mx, __shfl_xor(mx, 4));
            mx = fmaxf(mx, __shfl_xor(mx, 8));
            const float mn = fmaxf(mi[r], mx);
            const float al = __expf(mi[r] - mn);
            mi[r] = mn;
            float rs = 0.f;
#pragma unroll
            for (int kf = 0; kf < 4; ++kf) {
                const float p = __expf(s4[kf][r] - mn);
                s4[kf][r] = p;
                rs += p;
            }
            rs += __shfl_xor(rs, 1);
            rs += __shfl_xor(rs, 2);
            rs += __shfl_xor(rs, 4);
            rs += __shfl_xor(rs, 8);
            li[r] = li[r] * al + rs;
#pragma unroll
            for (int j = 0; j < 4; ++j) o[j][r] *= al;
#pragma unroll
            for (int kf = 0; kf < 4; ++kf)
                sP[w][(lg * 4 + r) * 72 + kf * 16 + lr] = f2bf(s4[kf][r]);
        }

        // ---- PV: o += P[16x64] * V[64x64] ----
#pragma unroll
        for (int ks = 0; ks < 2; ++ks) {
            bf16x8 pa = *(const bf16x8*)(&sP[w][lr * 72 + ks * 32 + lg * 8]);
#pragma unroll
            for (int jf = 0; jf < 4; ++jf) {
                const int row = jf * 16 + lr;
                bf16x8 vb = *(const bf16x8*)(sV + row * 64 + ((ks * 4 + lg) ^ (row & 7)) * 8);
                o[jf] = __builtin_amdgcn_mfma_f32_16x16x32_bf16(pa, vb, o[jf], 0, 0, 0);
            }
        }
    }

    // epilogue: normalize, write [B,S,D] bf16
    const int b = bh >> 4, h = bh & 15;
#pragma unroll
    for (int r = 0; r < 4; ++r) {
        const float inv = 1.f / li[r];
        const int s = qt * 64 + w * 16 + lg * 4 + r;
#pragma unroll
        for (int jf = 0; jf < 4; ++jf)
            Og[((size_t)b * S_ + s) * D_ + h * DK_ + jf * 16 + lr] = f2bf(o[jf][r] * inv);
    }
}

// ---------------------------------------------------------------------------
// Kernel: out = attn[4096][1024] @ Wo  (BT = WoT[1024][1024]), fp32 out
// ---------------------------------------------------------------------------
__global__ __launch_bounds__(256) void gemm_out(
    const u16* __restrict__ A, const u16* __restrict__ BT, float* __restrict__ C)
{
    __shared__ u16 lA[128 * 32];
    __shared__ u16 lB[128 * 32];
    const int t = threadIdx.x, l = t & 63, w = t >> 6;
    const int m0 = blockIdx.x * 128, n0 = blockIdx.y * 128;
    f32x4 acc[4][4] = {};
    gemm_mainloop_128(A, BT, 1024, m0, n0, l, w, lA, lB, acc);

    const int wr = w >> 1, wc = w & 1, lr = l & 15, lg = l >> 4;
#pragma unroll
    for (int j = 0; j < 4; ++j) {
        const int n = n0 + wc * 64 + j * 16 + lr;
#pragma unroll
        for (int i = 0; i < 4; ++i) {
#pragma unroll
            for (int r = 0; r < 4; ++r) {
                const int m = m0 + wr * 64 + i * 16 + lg * 4 + r;
                C[(size_t)m * D_ + n] = acc[i][j][r];
            }
        }
    }
}

// ---------------------------------------------------------------------------
extern "C" void kernel_launch(void* const* d_in, const int* in_sizes, int n_in,
                              void* d_out, int out_size, void* d_ws, size_t ws_size,
                              hipStream_t stream) {
    const float* X    = (const float*)d_in[0];  // [B,S,D]
    const int*   pos  = (const int*)d_in[1];    // [S]
    const float* Wqkv = (const float*)d_in[2];  // [D,3D]
    const float* Wo   = (const float*)d_in[3];  // [D,D]
    float* out = (float*)d_out;                 // [B,S,D] fp32

    char* ws = (char*)d_ws;
    u16*    Xb  = (u16*)(ws);                        // 8 MB
    u16*    WqT = (u16*)(ws + ((size_t)8  << 20));   // 6 MB
    u16*    WoT = (u16*)(ws + ((size_t)14 << 20));   // 2 MB
    float2* tab = (float2*)(ws + ((size_t)16 << 20)); // 0.5 MB
    u16*    Qb  = (u16*)(ws + ((size_t)17 << 20));   // 8 MB
    u16*    Kb  = (u16*)(ws + ((size_t)25 << 20));   // 8 MB
    u16*    VTb = (u16*)(ws + ((size_t)33 << 20));   // 8 MB
    u16*    AOb = (u16*)(ws + ((size_t)41 << 20));   // 8 MB

    cast_bf16_kernel<<<2048, 256, 0, stream>>>(X, Xb, B_ * S_ * D_);
    transpose_cast<<<dim3(16, 48), 256, 0, stream>>>(Wqkv, WqT, 3 * D_);
    transpose_cast<<<dim3(16, 16), 256, 0, stream>>>(Wo, WoT, D_);
    rope_table_kernel<<<256, 256, 0, stream>>>(pos, tab);

    gemm_qkv_rope<<<dim3(32, 24), 256, 0, stream>>>(Xb, WqT, tab, Qb, Kb, VTb);
    attn_mfma<<<dim3(32, 32), 256, 0, stream>>>(Qb, Kb, VTb, AOb);
    gemm_out<<<dim3(32, 8), 256, 0, stream>>>(AOb, WoT, out);
}